// Round 1
// baseline (218.560 us; speedup 1.0000x reference)
//
#include <hip/hip_runtime.h>
#include <hip/hip_bf16.h>

typedef __hip_bfloat16 bf16;
typedef __attribute__((ext_vector_type(8))) short short8;
typedef __attribute__((ext_vector_type(4))) float floatx4;

#define AS1 __attribute__((address_space(1)))
#define AS3 __attribute__((address_space(3)))

#define B_DIM 4096
#define K_DIM 1024
#define LN_TAU_STEP 1.15129254649702295f

// ---------------- transpose f32 [K][N] -> bf16 [N][K] ----------------
__global__ void transpose_bf16(const float* __restrict__ src, bf16* __restrict__ dst,
                               int K, int N) {
  __shared__ float tile[32][33];
  int n0 = blockIdx.x * 32, k0 = blockIdx.y * 32;
  int tx = threadIdx.x, ty = threadIdx.y;
#pragma unroll
  for (int i = 0; i < 32; i += 8)
    tile[ty + i][tx] = src[(size_t)(k0 + ty + i) * N + n0 + tx];
  __syncthreads();
#pragma unroll
  for (int i = 0; i < 32; i += 8)
    dst[(size_t)(n0 + ty + i) * K + k0 + tx] = __float2bfloat16(tile[tx][ty + i]);
}

// ---------------- build fused = [inputs | h], h = sum_m state ----------------
__global__ void build_fused(const float* __restrict__ inputs, const float* __restrict__ state,
                            bf16* __restrict__ fused, bf16* __restrict__ reset) {
  int idx = blockIdx.x * blockDim.x + threadIdx.x;  // b*512 + u
  int b = idx >> 9, u = idx & 511;
  float x = inputs[(size_t)b * 512 + u];
  bf16 xb = __float2bfloat16(x);
  fused[(size_t)b * 1024 + u] = xb;
  reset[(size_t)b * 1024 + u] = xb;
  const float* sp = state + (size_t)b * 4096 + u * 8;
  float s[8];
  *(float4*)(s)     = *(const float4*)(sp);
  *(float4*)(s + 4) = *(const float4*)(sp + 4);
  float h = 0.f;
#pragma unroll
  for (int m = 0; m < 8; ++m) h += s[m];
  fused[(size_t)b * 1024 + 512 + u] = __float2bfloat16(h);
}

// ---------------- bf16 MFMA GEMM: C[M][N] = A[M][K] @ Bt[N][K]^T + bias ----------------
// 128x128 tile, BK=32, 4 waves (2x2), each wave 64x64 via 4x4 x mfma 16x16x32.
template <bool TANH>
__global__ __launch_bounds__(256) void gemm_bf16(const bf16* __restrict__ A,
                                                 const bf16* __restrict__ Bt,
                                                 const float* __restrict__ bias,
                                                 float* __restrict__ C, int N) {
  __shared__ bf16 lA[128 * 32];
  __shared__ bf16 lB[128 * 32];
  const int tid = threadIdx.x;
  const int wave = tid >> 6;
  const int lane = tid & 63;
  const int g = lane >> 4;   // k-group (0..3)
  const int r = lane & 15;   // row/col within fragment
  const int wr = wave >> 1, wc = wave & 1;
  const int bm = blockIdx.y * 128;
  const int bn = blockIdx.x * 128;

  floatx4 acc[4][4] = {};

  // staging: each wave stages 32 rows of A-tile and 32 rows of B-tile,
  // 2 x global_load_lds(16B) each; lane l covers row wave*32+j*16+l/4, col (l%4)*8
  const int srow = wave * 32 + (lane >> 2);
  const int scol = (lane & 3) * 8;

  for (int kt = 0; kt < K_DIM; kt += 32) {
#pragma unroll
    for (int j = 0; j < 2; ++j) {
      const bf16* ga = A + (size_t)(bm + srow + j * 16) * K_DIM + kt + scol;
      __builtin_amdgcn_global_load_lds((AS1 const void*)(ga),
                                       (AS3 void*)(lA + (wave * 32 + j * 16) * 32), 16, 0, 0);
    }
#pragma unroll
    for (int j = 0; j < 2; ++j) {
      const bf16* gb = Bt + (size_t)(bn + srow + j * 16) * K_DIM + kt + scol;
      __builtin_amdgcn_global_load_lds((AS1 const void*)(gb),
                                       (AS3 void*)(lB + (wave * 32 + j * 16) * 32), 16, 0, 0);
    }
    __syncthreads();  // drains vmcnt before barrier (compiler-inserted)

    short8 aF[4], bF[4];
#pragma unroll
    for (int mi = 0; mi < 4; ++mi)
      aF[mi] = *(const short8*)(lA + (wr * 64 + mi * 16 + r) * 32 + g * 8);
#pragma unroll
    for (int ni = 0; ni < 4; ++ni)
      bF[ni] = *(const short8*)(lB + (wc * 64 + ni * 16 + r) * 32 + g * 8);
#pragma unroll
    for (int mi = 0; mi < 4; ++mi)
#pragma unroll
      for (int ni = 0; ni < 4; ++ni)
        acc[mi][ni] =
            __builtin_amdgcn_mfma_f32_16x16x32_bf16(aF[mi], bF[ni], acc[mi][ni], 0, 0, 0);
    __syncthreads();
  }

  // epilogue: D col = lane&15, row = (lane>>4)*4 + reg
#pragma unroll
  for (int mi = 0; mi < 4; ++mi) {
#pragma unroll
    for (int ni = 0; ni < 4; ++ni) {
      int col = bn + wc * 64 + ni * 16 + r;
      float bv = bias[col];
#pragma unroll
      for (int j = 0; j < 4; ++j) {
        int row = bm + wr * 64 + mi * 16 + g * 4 + j;
        float v = acc[mi][ni][j] + bv;
        if (TANH) v = tanhf(v);
        C[(size_t)row * N + col] = v;
      }
    }
  }
}

// ---------------- softmax over M of -(r - ln_tau)^2, q_input = sum(p * h_hat) ----------------
__global__ void softmax_r(const float* __restrict__ C, const float* __restrict__ state,
                          bf16* __restrict__ reset) {
  int idx = blockIdx.x * blockDim.x + threadIdx.x;  // b*512 + u
  int b = idx >> 9, u = idx & 511;
  const float* rp = C + (size_t)b * 4096 + u * 8;
  const float* sp = state + (size_t)b * 4096 + u * 8;
  float rr[8], ss[8];
  *(float4*)(rr)     = *(const float4*)(rp);
  *(float4*)(rr + 4) = *(const float4*)(rp + 4);
  *(float4*)(ss)     = *(const float4*)(sp);
  *(float4*)(ss + 4) = *(const float4*)(sp + 4);
  float lg[8], mx = -1e30f;
#pragma unroll
  for (int m = 0; m < 8; ++m) {
    float d = rr[m] - m * LN_TAU_STEP;
    lg[m] = -d * d;
    mx = fmaxf(mx, lg[m]);
  }
  float sum = 0.f, q = 0.f;
#pragma unroll
  for (int m = 0; m < 8; ++m) {
    float e = expf(lg[m] - mx);
    sum += e;
    q += e * ss[m];
  }
  reset[(size_t)b * 1024 + 512 + u] = __float2bfloat16(q / sum);
}

// ---------------- final: ski softmax, h_hat_next, h_next ----------------
__global__ void finalize(const float* __restrict__ C, const float* __restrict__ state,
                         const float* __restrict__ qk, float* __restrict__ out) {
  int idx = blockIdx.x * blockDim.x + threadIdx.x;  // b*512 + u
  int b = idx >> 9, u = idx & 511;
  const float* spx = C + (size_t)b * 4096 + u * 8;
  const float* hp = state + (size_t)b * 4096 + u * 8;
  float qv = qk[(size_t)b * 512 + u];
  float sl[8], hh[8];
  *(float4*)(sl)     = *(const float4*)(spx);
  *(float4*)(sl + 4) = *(const float4*)(spx + 4);
  *(float4*)(hh)     = *(const float4*)(hp);
  *(float4*)(hh + 4) = *(const float4*)(hp + 4);
  float lg[8], mx = -1e30f;
#pragma unroll
  for (int m = 0; m < 8; ++m) {
    float d = sl[m] - m * LN_TAU_STEP;
    lg[m] = -d * d;
    mx = fmaxf(mx, lg[m]);
  }
  float sum = 0.f;
  float e[8];
#pragma unroll
  for (int m = 0; m < 8; ++m) {
    e[m] = expf(lg[m] - mx);
    sum += e[m];
  }
  float inv = 1.f / sum;
  float hn = 0.f, res[8];
#pragma unroll
  for (int m = 0; m < 8; ++m) {
    float t = m * LN_TAU_STEP;
    float dec = (m == 0) ? 0.f : expf(-1.f / t);
    float s = e[m] * inv;
    float v = ((1.f - s) * hh[m] + s * qv) * dec;
    res[m] = v;
    hn += v;
  }
  out[(size_t)b * 512 + u] = hn;
  float* op = out + (size_t)4096 * 512 + (size_t)b * 4096 + u * 8;
  *(float4*)(op)     = *(const float4*)(res);
  *(float4*)(op + 4) = *(const float4*)(res + 4);
}

extern "C" void kernel_launch(void* const* d_in, const int* in_sizes, int n_in, void* d_out,
                              int out_size, void* d_ws, size_t ws_size, hipStream_t stream) {
  const float* inputs = (const float*)d_in[0];
  const float* state  = (const float*)d_in[1];
  const float* Wr     = (const float*)d_in[2];
  const float* br     = (const float*)d_in[3];
  const float* Ws     = (const float*)d_in[4];
  const float* bs     = (const float*)d_in[5];
  const float* Wq     = (const float*)d_in[6];
  const float* bq     = (const float*)d_in[7];
  float* out = (float*)d_out;

  char* ws = (char*)d_ws;
  bf16* Wrt   = (bf16*)(ws);                       // 8 MiB  [4096][1024]
  bf16* Wst   = (bf16*)(ws + (8ull << 20));        // 8 MiB
  bf16* Wqt   = (bf16*)(ws + (16ull << 20));       // 1 MiB  [512][1024]
  bf16* fused = (bf16*)(ws + (17ull << 20));       // 8 MiB  [4096][1024]
  bf16* reset = (bf16*)(ws + (25ull << 20));       // 8 MiB
  float* qk   = (float*)(ws + (33ull << 20));      // 8 MiB  [4096][512]
  float* Cbuf = (float*)(ws + (41ull << 20));      // 64 MiB [4096][4096]

  dim3 tb(32, 8);
  transpose_bf16<<<dim3(128, 32), tb, 0, stream>>>(Wr, Wrt, 1024, 4096);
  transpose_bf16<<<dim3(128, 32), tb, 0, stream>>>(Ws, Wst, 1024, 4096);
  transpose_bf16<<<dim3(16, 32), tb, 0, stream>>>(Wq, Wqt, 1024, 512);
  build_fused<<<8192, 256, 0, stream>>>(inputs, state, fused, reset);
  gemm_bf16<false><<<dim3(32, 32), 256, 0, stream>>>(fused, Wrt, br, Cbuf, 4096);
  softmax_r<<<8192, 256, 0, stream>>>(Cbuf, state, reset);
  gemm_bf16<true><<<dim3(4, 32), 256, 0, stream>>>(reset, Wqt, bq, qk, 512);
  gemm_bf16<false><<<dim3(32, 32), 256, 0, stream>>>(fused, Wst, bs, Cbuf, 4096);
  finalize<<<8192, 256, 0, stream>>>(Cbuf, state, qk, out);
}